// Round 3
// baseline (618.347 us; speedup 1.0000x reference)
//
#include <hip/hip_runtime.h>
#include <hip/hip_bf16.h>
#include <cstdint>
#include <cstddef>

// out[8192,4096] = x @ W^T + bias + 2*((x@A^T)@B^T)
// Fold: W' = W + 2*B@A (rank-16), then ONE bf16 MFMA GEMM: out = x @ W'^T + bias.
// R3: prep rewritten — grid-stride cast, 8 outstanding float4/thread (was
//     4 KB/block, 1 load/thread: latency-bound, ~131K tiny waves).
//     GEMM untouched (at m97-structure plateau, ~797 TF; in-structure tweaks
//     measured neutral per m99-m141).

#define IN_F   4096
#define OUT_F  4096
#define MROWS  8192   // 4*2048
#define RLORA  16
#define LORA_SCALE 2.0f

#define BM 128
#define BN 128
#define BK 32

#define FOLD_BLOCKS 4096                 // one per W' row
#define CAST_BLOCKS 4096                 // 1M threads x 8 float4 = 8M float4
#define CAST_VEC    (MROWS * IN_F / 4)   // 8M float4 total

typedef __bf16 bf16x8 __attribute__((ext_vector_type(8)));
typedef float  f32x4  __attribute__((ext_vector_type(4)));

__device__ __forceinline__ unsigned short f2bf_rne(float f) {
    union { float f; unsigned u; } v; v.f = f;
    unsigned u = v.u;
    return (unsigned short)((u + 0x7FFFu + ((u >> 16) & 1u)) >> 16);
}

__device__ __forceinline__ ushort4 cvt4(float4 v) {
    ushort4 o;
    o.x = f2bf_rne(v.x); o.y = f2bf_rne(v.y);
    o.z = f2bf_rne(v.z); o.w = f2bf_rne(v.w);
    return o;
}

__device__ __forceinline__ void gl_lds16(const unsigned short* g, unsigned short* l) {
    __builtin_amdgcn_global_load_lds(
        (const __attribute__((address_space(1))) unsigned int*)g,
        (__attribute__((address_space(3))) unsigned int*)l,
        16, 0, 0);
}

// ---- prep: blocks [0,4096) fold W'; [4096,8192) cast x fp32->bf16 ----------

__global__ void prep_kernel(const float* __restrict__ x,
                            const float* __restrict__ W,
                            const float* __restrict__ A,
                            const float* __restrict__ B,
                            unsigned short* __restrict__ xb,
                            unsigned short* __restrict__ wb) {
    __shared__ float sB[RLORA];
    const int bid = blockIdx.x;
    if (bid >= FOLD_BLOCKS) {
        // cast: 1M threads, each 8 coalesced float4 loads (independent -> MLP)
        const int gid    = (bid - FOLD_BLOCKS) * blockDim.x + threadIdx.x;
        const int stride = CAST_BLOCKS * 256;          // 1M threads
        const float4* x4 = (const float4*)x;
        ushort4*     xb4 = (ushort4*)xb;
        float4 v[8];
        #pragma unroll
        for (int j = 0; j < 8; ++j)
            v[j] = x4[(size_t)j * stride + gid];       // all loads issue first
        #pragma unroll
        for (int j = 0; j < 8; ++j)
            xb4[(size_t)j * stride + gid] = cvt4(v[j]);
    } else {
        const int o = bid;                             // W' output row
        if (threadIdx.x < RLORA) sB[threadIdx.x] = B[o * RLORA + threadIdx.x];
        __syncthreads();
        const float4* W4  = (const float4*)(W + (size_t)o * IN_F);
        ushort4*      Wp4 = (ushort4*)(wb + (size_t)o * IN_F);
        for (int i4 = threadIdx.x; i4 < IN_F / 4; i4 += blockDim.x) {
            float4 w = W4[i4];
            float ax = 0.f, ay = 0.f, az = 0.f, aw = 0.f;
            #pragma unroll
            for (int r = 0; r < RLORA; ++r) {
                float4 a = ((const float4*)(A + (size_t)r * IN_F))[i4];
                float s = sB[r];
                ax += s * a.x; ay += s * a.y; az += s * a.z; aw += s * a.w;
            }
            w.x += LORA_SCALE * ax; w.y += LORA_SCALE * ay;
            w.z += LORA_SCALE * az; w.w += LORA_SCALE * aw;
            float4 wf = make_float4(w.x, w.y, w.z, w.w);
            Wp4[i4] = cvt4(wf);
        }
    }
}

// ---- GEMM: C[M,N] = Xb @ Wb^T + bias (m97 structure, unchanged) ------------

__global__ __launch_bounds__(256)
void gemm_bt_bias(const unsigned short* __restrict__ Xb,
                  const unsigned short* __restrict__ Wb,
                  const float* __restrict__ bias,
                  float* __restrict__ out) {
    __shared__ __align__(16) unsigned short As[BM * BK];   // 8 KB
    __shared__ __align__(16) unsigned short Bs[BN * BK];   // 8 KB

    const int tid  = threadIdx.x;
    const int wave = tid >> 6;
    const int lane = tid & 63;
    const int quad = lane >> 4;
    const int r16  = lane & 15;
    const int wm   = wave >> 1;
    const int wn   = wave & 1;

    const int bid = blockIdx.x;
    const int xcd = bid & 7;
    const int t   = bid >> 3;
    const int n0  = ((xcd << 2) | (t & 3)) * BN;
    const int m0  = (t >> 2) * BM;

    const int c0   = wave * 128 + lane;
    const int c1   = c0 + 64;
    const int row0 = c0 >> 2, kc0 = c0 & 3;
    const int row1 = c1 >> 2, kc1 = c1 & 3;

    const unsigned short* gA0 = Xb + (size_t)(m0 + row0) * IN_F + kc0 * 8;
    const unsigned short* gA1 = Xb + (size_t)(m0 + row1) * IN_F + kc1 * 8;
    const unsigned short* gB0 = Wb + (size_t)(n0 + row0) * IN_F + kc0 * 8;
    const unsigned short* gB1 = Wb + (size_t)(n0 + row1) * IN_F + kc1 * 8;

    unsigned short* lA0 = As + (wave * 128 +  0) * 8;
    unsigned short* lA1 = As + (wave * 128 + 64) * 8;
    unsigned short* lB0 = Bs + (wave * 128 +  0) * 8;
    unsigned short* lB1 = Bs + (wave * 128 + 64) * 8;

    const unsigned short* pA = As + ((wm * 64 + r16) * BK) + quad * 8;
    const unsigned short* pB = Bs + ((wn * 64 + r16) * BK) + quad * 8;

    f32x4 acc[4][4] = {};

    for (int k0 = 0; k0 < IN_F; k0 += BK) {
        gl_lds16(gA0, lA0);
        gl_lds16(gA1, lA1);
        gl_lds16(gB0, lB0);
        gl_lds16(gB1, lB1);
        gA0 += BK; gA1 += BK; gB0 += BK; gB1 += BK;
        __syncthreads();

        bf16x8 aF[4], bF[4];
        #pragma unroll
        for (int mi = 0; mi < 4; ++mi)
            aF[mi] = *(const bf16x8*)(pA + mi * 16 * BK);
        #pragma unroll
        for (int ni = 0; ni < 4; ++ni)
            bF[ni] = *(const bf16x8*)(pB + ni * 16 * BK);

        #pragma unroll
        for (int mi = 0; mi < 4; ++mi)
            #pragma unroll
            for (int ni = 0; ni < 4; ++ni)
                acc[mi][ni] = __builtin_amdgcn_mfma_f32_16x16x32_bf16(
                    aF[mi], bF[ni], acc[mi][ni], 0, 0, 0);

        __syncthreads();
    }

    float bv[4];
    #pragma unroll
    for (int ni = 0; ni < 4; ++ni)
        bv[ni] = bias[n0 + wn * 64 + ni * 16 + r16];

    #pragma unroll
    for (int mi = 0; mi < 4; ++mi) {
        #pragma unroll
        for (int i = 0; i < 4; ++i) {
            int mg = m0 + wm * 64 + mi * 16 + quad * 4 + i;
            float* orow = out + (size_t)mg * OUT_F + (n0 + wn * 64 + r16);
            #pragma unroll
            for (int ni = 0; ni < 4; ++ni)
                orow[ni * 16] = acc[mi][ni][i] + bv[ni];
        }
    }
}

// ---- launch ----------------------------------------------------------------

extern "C" void kernel_launch(void* const* d_in, const int* in_sizes, int n_in,
                              void* d_out, int out_size, void* d_ws, size_t ws_size,
                              hipStream_t stream) {
    const float* x    = (const float*)d_in[0];
    const float* W    = (const float*)d_in[1];
    const float* bias = (const float*)d_in[2];
    const float* A    = (const float*)d_in[3];
    const float* B    = (const float*)d_in[4];
    float* out = (float*)d_out;

    unsigned short* xb = (unsigned short*)d_ws;              // 64 MB bf16 x
    unsigned short* wb = xb + (size_t)MROWS * IN_F;          // 32 MB bf16 W'

    prep_kernel<<<FOLD_BLOCKS + CAST_BLOCKS, 256, 0, stream>>>(x, W, A, B, xb, wb);
    gemm_bt_bias<<<2048, 256, 0, stream>>>(xb, wb, bias, out);
}